// Round 1
// baseline (449.467 us; speedup 1.0000x reference)
//
#include <hip/hip_runtime.h>
#include <cmath>

// n=50000 nodes, E=800000 edges, F=128 units, IN_F=5.
// Inputs (setup_inputs order):
// 0 x[n,5] f32, 1 edge_index[2,E] int, 2 batch[n] int,
// 3 Wl1[5,128], 4 bl1[128], 5 Wr1[5,128],
// 6 Wl2[128,128], 7 bl2[128], 8 Wr2[128,128],
// 9 Wla[128,1], 10 bla[1], 11 Wra[128,1],
// 12 Wlc[128,128], 13 blc[128], 14 Wrc[128,128], 15 Wf[128,1], 16 bf[1]
// Output: x_actor[n] (log_softmax) then x_critic[1] -> out_size = n+1 floats.

#define SCAN_B 256

__global__ void k_count(const int* __restrict__ ei, int* __restrict__ deg, int E) {
    int e = blockIdx.x * 256 + threadIdx.x;
    if (e >= E) return;
    int dst = ei[E + e];
    atomicAdd(&deg[dst], 1);
}

__global__ void k_blocksum(const int* __restrict__ deg, int* __restrict__ bsum, int n) {
    __shared__ int sd[SCAN_B];
    int i = blockIdx.x * SCAN_B + threadIdx.x;
    sd[threadIdx.x] = (i < n) ? deg[i] : 0;
    __syncthreads();
    for (int s = SCAN_B / 2; s > 0; s >>= 1) {
        if (threadIdx.x < s) sd[threadIdx.x] += sd[threadIdx.x + s];
        __syncthreads();
    }
    if (threadIdx.x == 0) bsum[blockIdx.x] = sd[0];
}

__global__ void k_scan_bsum(int* __restrict__ bsum, int nb) {
    // single block, 1024 threads; exclusive scan of bsum[0..nb)
    __shared__ int sd[1024];
    int t = threadIdx.x;
    int v = (t < nb) ? bsum[t] : 0;
    sd[t] = v;
    __syncthreads();
    for (int off = 1; off < 1024; off <<= 1) {
        int add = (t >= off) ? sd[t - off] : 0;
        __syncthreads();
        sd[t] += add;
        __syncthreads();
    }
    if (t < nb) bsum[t] = sd[t] - v; // exclusive
}

__global__ void k_scan_final(const int* __restrict__ deg, const int* __restrict__ bsum,
                             int* __restrict__ row_ptr, int* __restrict__ fill_pos,
                             float* __restrict__ inv_deg, int n) {
    __shared__ int sd[SCAN_B];
    int t = threadIdx.x;
    int i = blockIdx.x * SCAN_B + t;
    int v = (i < n) ? deg[i] : 0;
    sd[t] = v;
    __syncthreads();
    for (int off = 1; off < SCAN_B; off <<= 1) {
        int add = (t >= off) ? sd[t - off] : 0;
        __syncthreads();
        sd[t] += add;
        __syncthreads();
    }
    if (i < n) {
        int excl = bsum[blockIdx.x] + sd[t] - v;
        row_ptr[i] = excl;
        fill_pos[i] = excl;
        inv_deg[i] = 1.0f / fmaxf((float)v, 1.0f);
        if (i == n - 1) row_ptr[n] = excl + v;
    }
}

__global__ void k_fill(const int* __restrict__ ei, int* __restrict__ fill_pos,
                       int* __restrict__ edge_src, int E) {
    int e = blockIdx.x * 256 + threadIdx.x;
    if (e >= E) return;
    int src = ei[e];
    int dst = ei[E + e];
    int pos = atomicAdd(&fill_pos[dst], 1);
    edge_src[pos] = src;
}

// aggregate 5-dim input x by dst (mean) -> agg0[n,5]
__global__ void k_agg0(const float* __restrict__ x, const int* __restrict__ row_ptr,
                       const int* __restrict__ edge_src, const float* __restrict__ inv_deg,
                       float* __restrict__ agg0, int n) {
    int i = blockIdx.x * 256 + threadIdx.x;
    if (i >= n) return;
    float a0 = 0, a1 = 0, a2 = 0, a3 = 0, a4 = 0;
    int s = row_ptr[i], e = row_ptr[i + 1];
    for (int t = s; t < e; ++t) {
        const float* xp = x + (size_t)edge_src[t] * 5;
        a0 += xp[0]; a1 += xp[1]; a2 += xp[2]; a3 += xp[3]; a4 += xp[4];
    }
    float iv = inv_deg[i];
    float* o = agg0 + (size_t)i * 5;
    o[0] = a0 * iv; o[1] = a1 * iv; o[2] = a2 * iv; o[3] = a3 * iv; o[4] = a4 * iv;
}

// h1[i,j] = tanh(agg0[i,:]@Wl1[:,j] + bl1[j] + x[i,:]@Wr1[:,j]); block (128,2)
__global__ void k_h1(const float* __restrict__ x, const float* __restrict__ agg0,
                     const float* __restrict__ Wl1, const float* __restrict__ bl1,
                     const float* __restrict__ Wr1, float* __restrict__ h1, int n) {
    __shared__ float sA[2][5], sX[2][5];
    int node = blockIdx.x * 2 + threadIdx.y;
    int j = threadIdx.x;
    if (node < n && j < 5) {
        sA[threadIdx.y][j] = agg0[(size_t)node * 5 + j];
        sX[threadIdx.y][j] = x[(size_t)node * 5 + j];
    }
    __syncthreads();
    if (node >= n) return;
    float acc = bl1[j];
#pragma unroll
    for (int k = 0; k < 5; k++)
        acc += sA[threadIdx.y][k] * Wl1[k * 128 + j] + sX[threadIdx.y][k] * Wr1[k * 128 + j];
    h1[(size_t)node * 128 + j] = tanhf(acc);
}

// wave-per-node 128-dim mean aggregation: agg[i,:] = inv_deg[i]*sum_{src} h[src,:]
// block (64,4)
__global__ void k_agg128(const float* __restrict__ h, const int* __restrict__ row_ptr,
                         const int* __restrict__ edge_src, const float* __restrict__ inv_deg,
                         float* __restrict__ agg, int n) {
    int node = blockIdx.x * 4 + threadIdx.y;
    if (node >= n) return;
    int lane = threadIdx.x;
    int s = row_ptr[node], e = row_ptr[node + 1];
    float ax = 0.f, ay = 0.f;
    for (int t = s; t < e; ++t) {
        int src = edge_src[t];
        float2 v = ((const float2*)(h + (size_t)src * 128))[lane];
        ax += v.x; ay += v.y;
    }
    float iv = inv_deg[node];
    float2 o; o.x = ax * iv; o.y = ay * iv;
    ((float2*)(agg + (size_t)node * 128))[lane] = o;
}

// h2 = tanh(agg1@Wl2 + bl2 + h1@Wr2); block (32,8); each thread 4 rows x 4 cols
__global__ void k_h2(const float* __restrict__ agg1, const float* __restrict__ h1,
                     const float* __restrict__ Wl2, const float* __restrict__ bl2,
                     const float* __restrict__ Wr2, float* __restrict__ h2, int n) {
    int j0 = threadIdx.x * 4;
    int i0 = blockIdx.x * 32 + threadIdx.y * 4;
    float acc[4][4] = {};
    if (i0 + 3 < n) {
        for (int k = 0; k < 128; k += 4) {
            float4 wl[4], wr[4];
#pragma unroll
            for (int kk = 0; kk < 4; kk++) {
                wl[kk] = *(const float4*)(Wl2 + (size_t)(k + kk) * 128 + j0);
                wr[kk] = *(const float4*)(Wr2 + (size_t)(k + kk) * 128 + j0);
            }
#pragma unroll
            for (int r = 0; r < 4; r++) {
                float4 a = *(const float4*)(agg1 + (size_t)(i0 + r) * 128 + k);
                float4 h = *(const float4*)(h1 + (size_t)(i0 + r) * 128 + k);
                float av[4] = {a.x, a.y, a.z, a.w};
                float hv[4] = {h.x, h.y, h.z, h.w};
#pragma unroll
                for (int kk = 0; kk < 4; kk++) {
                    acc[r][0] += av[kk] * wl[kk].x + hv[kk] * wr[kk].x;
                    acc[r][1] += av[kk] * wl[kk].y + hv[kk] * wr[kk].y;
                    acc[r][2] += av[kk] * wl[kk].z + hv[kk] * wr[kk].z;
                    acc[r][3] += av[kk] * wl[kk].w + hv[kk] * wr[kk].w;
                }
            }
        }
    } else {
        for (int k = 0; k < 128; k++) {
            float wlv[4], wrv[4];
#pragma unroll
            for (int c = 0; c < 4; c++) {
                wlv[c] = Wl2[(size_t)k * 128 + j0 + c];
                wrv[c] = Wr2[(size_t)k * 128 + j0 + c];
            }
#pragma unroll
            for (int r = 0; r < 4; r++) {
                int i = i0 + r;
                if (i >= n) continue;
                float a = agg1[(size_t)i * 128 + k];
                float h = h1[(size_t)i * 128 + k];
#pragma unroll
                for (int c = 0; c < 4; c++) acc[r][c] += a * wlv[c] + h * wrv[c];
            }
        }
    }
    float4 b = *(const float4*)(bl2 + j0);
#pragma unroll
    for (int r = 0; r < 4; r++) {
        int i = i0 + r;
        if (i >= n) continue;
        float4 o;
        o.x = tanhf(acc[r][0] + b.x);
        o.y = tanhf(acc[r][1] + b.y);
        o.z = tanhf(acc[r][2] + b.z);
        o.w = tanhf(acc[r][3] + b.w);
        *(float4*)(h2 + (size_t)i * 128 + j0) = o;
    }
}

// wcomb[0:128]=Wlc@Wf, wcomb[128:256]=Wrc@Wf, wcomb[256]=blc.Wf+bf; 1 block x 128
__global__ void k_prep(const float* __restrict__ Wlc, const float* __restrict__ blc,
                       const float* __restrict__ Wrc, const float* __restrict__ Wf,
                       const float* __restrict__ bf, float* __restrict__ wcomb) {
    int k = threadIdx.x;
    float sl = 0.f, sr = 0.f;
    for (int j = 0; j < 128; j++) {
        float wf = Wf[j];
        sl += Wlc[(size_t)k * 128 + j] * wf;
        sr += Wrc[(size_t)k * 128 + j] * wf;
    }
    wcomb[k] = sl;
    wcomb[128 + k] = sr;
    __shared__ float sd[128];
    sd[k] = blc[k] * Wf[k];
    __syncthreads();
    for (int s = 64; s > 0; s >>= 1) {
        if (k < s) sd[k] += sd[k + s];
        __syncthreads();
    }
    if (k == 0) wcomb[256] = sd[0] + bf[0];
}

// wave-per-node: aggregate h2, fuse actor + critic head dots. block (64,4)
__global__ void k_heads(const float* __restrict__ h2, const int* __restrict__ row_ptr,
                        const int* __restrict__ edge_src, const float* __restrict__ inv_deg,
                        const float* __restrict__ x,
                        const float* __restrict__ Wla, const float* __restrict__ bla,
                        const float* __restrict__ Wra, const float* __restrict__ wcomb,
                        float* __restrict__ actor_s, float* __restrict__ critic_v, int n) {
    int node = blockIdx.x * 4 + threadIdx.y;
    if (node >= n) return;
    int lane = threadIdx.x;
    int s = row_ptr[node], e = row_ptr[node + 1];
    float ax = 0.f, ay = 0.f;
    for (int t = s; t < e; ++t) {
        int src = edge_src[t];
        float2 v = ((const float2*)(h2 + (size_t)src * 128))[lane];
        ax += v.x; ay += v.y;
    }
    float iv = inv_deg[node];
    float a0 = ax * iv, a1 = ay * iv;
    float2 hv = ((const float2*)(h2 + (size_t)node * 128))[lane];
    int f0 = 2 * lane, f1 = 2 * lane + 1;
    float pa = a0 * Wla[f0] + a1 * Wla[f1] + hv.x * Wra[f0] + hv.y * Wra[f1];
    float pc = a0 * wcomb[f0] + a1 * wcomb[f1] + hv.x * wcomb[128 + f0] + hv.y * wcomb[128 + f1];
#pragma unroll
    for (int off = 32; off >= 1; off >>= 1) {
        pa += __shfl_xor(pa, off);
        pc += __shfl_xor(pc, off);
    }
    if (lane == 0) {
        float sc = pa + bla[0];
        if (x[(size_t)node * 5 + 2] != 0.0f) sc = -INFINITY;
        actor_s[node] = sc;
        critic_v[node] = pc + wcomb[256];
    }
}

// single block 1024: logsumexp(actor_s) -> scalars[0]; critic mean+tanh -> d_out[n]
__global__ void k_reduce(const float* __restrict__ actor_s, const float* __restrict__ critic_v,
                         float* __restrict__ scalars, float* __restrict__ d_out, int n) {
    __shared__ float sm[1024], ss[1024], sc[1024];
    int t = threadIdx.x;
    float m = -INFINITY, sum = 0.f, cs = 0.f;
    for (int i = t; i < n; i += 1024) {
        cs += critic_v[i];
        float s = actor_s[i];
        if (s == -INFINITY) continue;
        if (s > m) {
            sum = sum * expf(m - s);
            m = s;
        }
        sum += expf(s - m);
    }
    sm[t] = m; ss[t] = sum; sc[t] = cs;
    __syncthreads();
    for (int s2 = 512; s2 > 0; s2 >>= 1) {
        if (t < s2) {
            float m2 = sm[t + s2], v2 = ss[t + s2];
            float M = fmaxf(sm[t], m2);
            if (M == -INFINITY) {
                ss[t] = 0.f;
            } else {
                ss[t] = ss[t] * expf(sm[t] - M) + v2 * expf(m2 - M);
            }
            sm[t] = M;
            sc[t] += sc[t + s2];
        }
        __syncthreads();
    }
    if (t == 0) {
        scalars[0] = sm[0] + logf(ss[0]);
        d_out[n] = tanhf(sc[0] / (float)n);
    }
}

__global__ void k_final(const float* __restrict__ actor_s, const float* __restrict__ scalars,
                        float* __restrict__ d_out, int n) {
    int i = blockIdx.x * 256 + threadIdx.x;
    if (i >= n) return;
    d_out[i] = actor_s[i] - scalars[0];
}

extern "C" void kernel_launch(void* const* d_in, const int* in_sizes, int n_in,
                              void* d_out, int out_size, void* d_ws, size_t ws_size,
                              hipStream_t stream) {
    const float* x   = (const float*)d_in[0];
    const int*   ei  = (const int*)d_in[1];
    const float* Wl1 = (const float*)d_in[3];
    const float* bl1 = (const float*)d_in[4];
    const float* Wr1 = (const float*)d_in[5];
    const float* Wl2 = (const float*)d_in[6];
    const float* bl2 = (const float*)d_in[7];
    const float* Wr2 = (const float*)d_in[8];
    const float* Wla = (const float*)d_in[9];
    const float* bla = (const float*)d_in[10];
    const float* Wra = (const float*)d_in[11];
    const float* Wlc = (const float*)d_in[12];
    const float* blc = (const float*)d_in[13];
    const float* Wrc = (const float*)d_in[14];
    const float* Wf  = (const float*)d_in[15];
    const float* bf  = (const float*)d_in[16];

    const int n = in_sizes[0] / 5;
    const int E = in_sizes[1] / 2;
    float* out = (float*)d_out;

    // workspace carve-up (256B aligned)
    char* w = (char*)d_ws;
    auto alloc = [&](size_t bytes) -> void* {
        void* p = (void*)w;
        w += (bytes + 255) & ~(size_t)255;
        return p;
    };
    int* deg      = (int*)alloc((size_t)n * 4);
    int* row_ptr  = (int*)alloc((size_t)(n + 1) * 4);
    int* fill_pos = (int*)alloc((size_t)n * 4);
    int* bsum     = (int*)alloc(1024 * 4);
    int* edge_src = (int*)alloc((size_t)E * 4);
    float* inv_deg = (float*)alloc((size_t)n * 4);
    float* agg0    = (float*)alloc((size_t)n * 5 * 4);
    float* h1      = (float*)alloc((size_t)n * 128 * 4);
    float* agg1    = (float*)alloc((size_t)n * 128 * 4);
    float* h2      = (float*)alloc((size_t)n * 128 * 4);
    float* actor_s = (float*)alloc((size_t)n * 4);
    float* critic_v= (float*)alloc((size_t)n * 4);
    float* wcomb   = (float*)alloc(260 * 4);
    float* scalars = (float*)alloc(16);

    hipMemsetAsync(deg, 0, (size_t)n * 4, stream);

    const int nbE = (E + 255) / 256;
    const int nbN = (n + 255) / 256;
    const int nbScan = (n + SCAN_B - 1) / SCAN_B;

    k_count<<<nbE, 256, 0, stream>>>(ei, deg, E);
    k_blocksum<<<nbScan, SCAN_B, 0, stream>>>(deg, bsum, n);
    k_scan_bsum<<<1, 1024, 0, stream>>>(bsum, nbScan);
    k_scan_final<<<nbScan, SCAN_B, 0, stream>>>(deg, bsum, row_ptr, fill_pos, inv_deg, n);
    k_fill<<<nbE, 256, 0, stream>>>(ei, fill_pos, edge_src, E);

    k_agg0<<<nbN, 256, 0, stream>>>(x, row_ptr, edge_src, inv_deg, agg0, n);
    k_h1<<<(n + 1) / 2, dim3(128, 2), 0, stream>>>(x, agg0, Wl1, bl1, Wr1, h1, n);

    k_agg128<<<(n + 3) / 4, dim3(64, 4), 0, stream>>>(h1, row_ptr, edge_src, inv_deg, agg1, n);
    k_h2<<<(n + 31) / 32, dim3(32, 8), 0, stream>>>(agg1, h1, Wl2, bl2, Wr2, h2, n);

    k_prep<<<1, 128, 0, stream>>>(Wlc, blc, Wrc, Wf, bf, wcomb);
    k_heads<<<(n + 3) / 4, dim3(64, 4), 0, stream>>>(h2, row_ptr, edge_src, inv_deg, x,
                                                     Wla, bla, Wra, wcomb, actor_s, critic_v, n);
    k_reduce<<<1, 1024, 0, stream>>>(actor_s, critic_v, scalars, out, n);
    k_final<<<nbN, 256, 0, stream>>>(actor_s, scalars, out, n);
}

// Round 2
// 361.277 us; speedup vs baseline: 1.2441x; 1.2441x over previous
//
#include <hip/hip_runtime.h>
#include <cmath>

// n=50000 nodes, E=800000 edges, F=128 units, IN_F=5.
// Output: x_actor[n] (log_softmax) then x_critic[1] -> out_size = n+1 floats.
//
// Pipeline (bf16 hidden path):
//  CSR build (count/scan/fill)
//  agg0 (5-dim mean), h1 = tanh(...) -> bf16 into Acat[:,128:256]
//  agg128: gather bf16 h1, mean -> bf16 into Acat[:,0:128]
//  h2 = tanh([agg1|h1] @ [Wl2;Wr2] + bl2) via MFMA bf16 -> h2b bf16
//  heads: gather bf16 h2, actor dot + folded critic dot (Wlc@Wf etc.)
//  reduce: logsumexp + critic mean/tanh; final: subtract lse

#define SCAN_B 256

typedef short short8 __attribute__((ext_vector_type(8)));
typedef float f32x4 __attribute__((ext_vector_type(4)));

__device__ __forceinline__ unsigned short f2b(float f) {
    union { float f; unsigned int u; } v; v.f = f;
    unsigned int r = (v.u + 0x7FFFu + ((v.u >> 16) & 1u)) >> 16;
    return (unsigned short)r;
}
__device__ __forceinline__ float b2f_lo(unsigned int u) {
    union { unsigned int u; float f; } v; v.u = u << 16; return v.f;
}
__device__ __forceinline__ float b2f_hi(unsigned int u) {
    union { unsigned int u; float f; } v; v.u = u & 0xFFFF0000u; return v.f;
}

__global__ void k_count(const int* __restrict__ ei, int* __restrict__ deg, int E) {
    int e = blockIdx.x * 256 + threadIdx.x;
    if (e >= E) return;
    atomicAdd(&deg[ei[E + e]], 1);
}

__global__ void k_blocksum(const int* __restrict__ deg, int* __restrict__ bsum, int n) {
    __shared__ int sd[SCAN_B];
    int i = blockIdx.x * SCAN_B + threadIdx.x;
    sd[threadIdx.x] = (i < n) ? deg[i] : 0;
    __syncthreads();
    for (int s = SCAN_B / 2; s > 0; s >>= 1) {
        if (threadIdx.x < s) sd[threadIdx.x] += sd[threadIdx.x + s];
        __syncthreads();
    }
    if (threadIdx.x == 0) bsum[blockIdx.x] = sd[0];
}

__global__ void k_scan_bsum(int* __restrict__ bsum, int nb) {
    __shared__ int sd[1024];
    int t = threadIdx.x;
    int v = (t < nb) ? bsum[t] : 0;
    sd[t] = v;
    __syncthreads();
    for (int off = 1; off < 1024; off <<= 1) {
        int add = (t >= off) ? sd[t - off] : 0;
        __syncthreads();
        sd[t] += add;
        __syncthreads();
    }
    if (t < nb) bsum[t] = sd[t] - v;
}

__global__ void k_scan_final(const int* __restrict__ deg, const int* __restrict__ bsum,
                             int* __restrict__ row_ptr, int* __restrict__ fill_pos,
                             float* __restrict__ inv_deg, int n) {
    __shared__ int sd[SCAN_B];
    int t = threadIdx.x;
    int i = blockIdx.x * SCAN_B + t;
    int v = (i < n) ? deg[i] : 0;
    sd[t] = v;
    __syncthreads();
    for (int off = 1; off < SCAN_B; off <<= 1) {
        int add = (t >= off) ? sd[t - off] : 0;
        __syncthreads();
        sd[t] += add;
        __syncthreads();
    }
    if (i < n) {
        int excl = bsum[blockIdx.x] + sd[t] - v;
        row_ptr[i] = excl;
        fill_pos[i] = excl;
        inv_deg[i] = 1.0f / fmaxf((float)v, 1.0f);
        if (i == n - 1) row_ptr[n] = excl + v;
    }
}

__global__ void k_fill(const int* __restrict__ ei, int* __restrict__ fill_pos,
                       int* __restrict__ edge_src, int E) {
    int e = blockIdx.x * 256 + threadIdx.x;
    if (e >= E) return;
    int src = ei[e];
    int dst = ei[E + e];
    int pos = atomicAdd(&fill_pos[dst], 1);
    edge_src[pos] = src;
}

__global__ void k_agg0(const float* __restrict__ x, const int* __restrict__ row_ptr,
                       const int* __restrict__ edge_src, const float* __restrict__ inv_deg,
                       float* __restrict__ agg0, int n) {
    int i = blockIdx.x * 256 + threadIdx.x;
    if (i >= n) return;
    float a0 = 0, a1 = 0, a2 = 0, a3 = 0, a4 = 0;
    int s = row_ptr[i], e = row_ptr[i + 1];
    for (int t = s; t < e; ++t) {
        const float* xp = x + (size_t)edge_src[t] * 5;
        a0 += xp[0]; a1 += xp[1]; a2 += xp[2]; a3 += xp[3]; a4 += xp[4];
    }
    float iv = inv_deg[i];
    float* o = agg0 + (size_t)i * 5;
    o[0] = a0 * iv; o[1] = a1 * iv; o[2] = a2 * iv; o[3] = a3 * iv; o[4] = a4 * iv;
}

// h1[i,j] = tanh(agg0[i,:]@Wl1[:,j] + bl1[j] + x[i,:]@Wr1[:,j]) -> bf16 into Acat[:,128+j]
__global__ void k_h1(const float* __restrict__ x, const float* __restrict__ agg0,
                     const float* __restrict__ Wl1, const float* __restrict__ bl1,
                     const float* __restrict__ Wr1, unsigned short* __restrict__ Acat, int n) {
    __shared__ float sA[2][5], sX[2][5];
    int node = blockIdx.x * 2 + threadIdx.y;
    int j = threadIdx.x;
    if (node < n && j < 5) {
        sA[threadIdx.y][j] = agg0[(size_t)node * 5 + j];
        sX[threadIdx.y][j] = x[(size_t)node * 5 + j];
    }
    __syncthreads();
    if (node >= n) return;
    float acc = bl1[j];
#pragma unroll
    for (int k = 0; k < 5; k++)
        acc += sA[threadIdx.y][k] * Wl1[k * 128 + j] + sX[threadIdx.y][k] * Wr1[k * 128 + j];
    Acat[(size_t)node * 256 + 128 + j] = f2b(tanhf(acc));
}

// wave-per-node bf16 mean aggregation of h1 (Acat cols 128:256) -> Acat cols 0:128
__global__ void k_agg128(unsigned short* __restrict__ Acat, const int* __restrict__ row_ptr,
                         const int* __restrict__ edge_src, const float* __restrict__ inv_deg,
                         int n) {
    int node = blockIdx.x * 4 + threadIdx.y;
    if (node >= n) return;
    int lane = threadIdx.x;
    int s = row_ptr[node], e = row_ptr[node + 1];
    float ax = 0.f, ay = 0.f;
    for (int t = s; t < e; ++t) {
        int src = edge_src[t];
        unsigned int u = ((const unsigned int*)(Acat + (size_t)src * 256 + 128))[lane];
        ax += b2f_lo(u);
        ay += b2f_hi(u);
    }
    float iv = inv_deg[node];
    unsigned int out = (unsigned int)f2b(ax * iv) | ((unsigned int)f2b(ay * iv) << 16);
    ((unsigned int*)(Acat + (size_t)node * 256))[lane] = out;
}

// WT[j][k] = bf16( k<128 ? Wl2[k][j] : Wr2[k-128][j] )  -- 128x256
__global__ void k_prepw(const float* __restrict__ Wl2, const float* __restrict__ Wr2,
                        unsigned short* __restrict__ WT) {
    int j = blockIdx.x;
    int k = threadIdx.x;
    float v = (k < 128) ? Wl2[(size_t)k * 128 + j] : Wr2[(size_t)(k - 128) * 128 + j];
    WT[(size_t)j * 256 + k] = f2b(v);
}

// h2b = bf16(tanh( Acat[n,256] @ WT^T + bl2 ))  via MFMA 16x16x32 bf16.
// block 256 = 4 waves; block tile 64 rows x 128 cols; wave tile 16 rows x 128 cols.
__global__ void k_h2_mfma(const unsigned short* __restrict__ Acat,
                          const unsigned short* __restrict__ WT,
                          const float* __restrict__ bl2,
                          unsigned short* __restrict__ h2b, int n) {
    int wave = threadIdx.x >> 6;
    int lane = threadIdx.x & 63;
    int r = lane & 15;   // A row-in-tile, B/D col-in-tile
    int g = lane >> 4;   // k-group
    int rowbase = blockIdx.x * 64 + wave * 16;
    int arow = rowbase + r;
    if (arow > n - 1) arow = n - 1;

    short8 a[8];
    const short* ap = (const short*)(Acat + (size_t)arow * 256 + g * 8);
#pragma unroll
    for (int kk = 0; kk < 8; kk++)
        a[kk] = *(const short8*)(ap + kk * 32);

#pragma unroll
    for (int nt = 0; nt < 8; nt++) {
        f32x4 acc = {0.f, 0.f, 0.f, 0.f};
        const short* bp = (const short*)(WT + (size_t)(nt * 16 + r) * 256 + g * 8);
#pragma unroll
        for (int kk = 0; kk < 8; kk++) {
            short8 b = *(const short8*)(bp + kk * 32);
            acc = __builtin_amdgcn_mfma_f32_16x16x32_bf16(a[kk], b, acc, 0, 0, 0);
        }
        int col = nt * 16 + r;
        float bj = bl2[col];
#pragma unroll
        for (int q = 0; q < 4; q++) {
            int rr = rowbase + g * 4 + q;
            if (rr < n) h2b[(size_t)rr * 128 + col] = f2b(tanhf(acc[q] + bj));
        }
    }
}

// wcomb[0:128]=Wlc@Wf, wcomb[128:256]=Wrc@Wf, wcomb[256]=blc.Wf+bf
__global__ void k_prep(const float* __restrict__ Wlc, const float* __restrict__ blc,
                       const float* __restrict__ Wrc, const float* __restrict__ Wf,
                       const float* __restrict__ bf, float* __restrict__ wcomb) {
    int k = threadIdx.x;
    float sl = 0.f, sr = 0.f;
    for (int j = 0; j < 128; j++) {
        float wf = Wf[j];
        sl += Wlc[(size_t)k * 128 + j] * wf;
        sr += Wrc[(size_t)k * 128 + j] * wf;
    }
    wcomb[k] = sl;
    wcomb[128 + k] = sr;
    __shared__ float sd[128];
    sd[k] = blc[k] * Wf[k];
    __syncthreads();
    for (int s = 64; s > 0; s >>= 1) {
        if (k < s) sd[k] += sd[k + s];
        __syncthreads();
    }
    if (k == 0) wcomb[256] = sd[0] + bf[0];
}

// wave-per-node: aggregate bf16 h2, fuse actor + folded critic head dots.
__global__ void k_heads(const unsigned short* __restrict__ h2b, const int* __restrict__ row_ptr,
                        const int* __restrict__ edge_src, const float* __restrict__ inv_deg,
                        const float* __restrict__ x,
                        const float* __restrict__ Wla, const float* __restrict__ bla,
                        const float* __restrict__ Wra, const float* __restrict__ wcomb,
                        float* __restrict__ actor_s, float* __restrict__ critic_v, int n) {
    int node = blockIdx.x * 4 + threadIdx.y;
    if (node >= n) return;
    int lane = threadIdx.x;
    int s = row_ptr[node], e = row_ptr[node + 1];
    float ax = 0.f, ay = 0.f;
    for (int t = s; t < e; ++t) {
        int src = edge_src[t];
        unsigned int u = ((const unsigned int*)(h2b + (size_t)src * 128))[lane];
        ax += b2f_lo(u);
        ay += b2f_hi(u);
    }
    float iv = inv_deg[node];
    float a0 = ax * iv, a1 = ay * iv;
    unsigned int uh = ((const unsigned int*)(h2b + (size_t)node * 128))[lane];
    float h0 = b2f_lo(uh), h1v = b2f_hi(uh);
    int f0 = 2 * lane, f1 = 2 * lane + 1;
    float pa = a0 * Wla[f0] + a1 * Wla[f1] + h0 * Wra[f0] + h1v * Wra[f1];
    float pc = a0 * wcomb[f0] + a1 * wcomb[f1] + h0 * wcomb[128 + f0] + h1v * wcomb[128 + f1];
#pragma unroll
    for (int off = 32; off >= 1; off >>= 1) {
        pa += __shfl_xor(pa, off);
        pc += __shfl_xor(pc, off);
    }
    if (lane == 0) {
        float sc = pa + bla[0];
        if (x[(size_t)node * 5 + 2] != 0.0f) sc = -INFINITY;
        actor_s[node] = sc;
        critic_v[node] = pc + wcomb[256];
    }
}

__global__ void k_reduce(const float* __restrict__ actor_s, const float* __restrict__ critic_v,
                         float* __restrict__ scalars, float* __restrict__ d_out, int n) {
    __shared__ float sm[1024], ss[1024], sc[1024];
    int t = threadIdx.x;
    float m = -INFINITY, sum = 0.f, cs = 0.f;
    for (int i = t; i < n; i += 1024) {
        cs += critic_v[i];
        float s = actor_s[i];
        if (s == -INFINITY) continue;
        if (s > m) {
            sum = sum * expf(m - s);
            m = s;
        }
        sum += expf(s - m);
    }
    sm[t] = m; ss[t] = sum; sc[t] = cs;
    __syncthreads();
    for (int s2 = 512; s2 > 0; s2 >>= 1) {
        if (t < s2) {
            float m2 = sm[t + s2], v2 = ss[t + s2];
            float M = fmaxf(sm[t], m2);
            if (M == -INFINITY) {
                ss[t] = 0.f;
            } else {
                ss[t] = ss[t] * expf(sm[t] - M) + v2 * expf(m2 - M);
            }
            sm[t] = M;
            sc[t] += sc[t + s2];
        }
        __syncthreads();
    }
    if (t == 0) {
        scalars[0] = sm[0] + logf(ss[0]);
        d_out[n] = tanhf(sc[0] / (float)n);
    }
}

__global__ void k_final(const float* __restrict__ actor_s, const float* __restrict__ scalars,
                        float* __restrict__ d_out, int n) {
    int i = blockIdx.x * 256 + threadIdx.x;
    if (i >= n) return;
    d_out[i] = actor_s[i] - scalars[0];
}

extern "C" void kernel_launch(void* const* d_in, const int* in_sizes, int n_in,
                              void* d_out, int out_size, void* d_ws, size_t ws_size,
                              hipStream_t stream) {
    const float* x   = (const float*)d_in[0];
    const int*   ei  = (const int*)d_in[1];
    const float* Wl1 = (const float*)d_in[3];
    const float* bl1 = (const float*)d_in[4];
    const float* Wr1 = (const float*)d_in[5];
    const float* Wl2 = (const float*)d_in[6];
    const float* bl2 = (const float*)d_in[7];
    const float* Wr2 = (const float*)d_in[8];
    const float* Wla = (const float*)d_in[9];
    const float* bla = (const float*)d_in[10];
    const float* Wra = (const float*)d_in[11];
    const float* Wlc = (const float*)d_in[12];
    const float* blc = (const float*)d_in[13];
    const float* Wrc = (const float*)d_in[14];
    const float* Wf  = (const float*)d_in[15];
    const float* bf  = (const float*)d_in[16];

    const int n = in_sizes[0] / 5;
    const int E = in_sizes[1] / 2;
    float* out = (float*)d_out;

    char* w = (char*)d_ws;
    auto alloc = [&](size_t bytes) -> void* {
        void* p = (void*)w;
        w += (bytes + 255) & ~(size_t)255;
        return p;
    };
    int* deg      = (int*)alloc((size_t)n * 4);
    int* row_ptr  = (int*)alloc((size_t)(n + 1) * 4);
    int* fill_pos = (int*)alloc((size_t)n * 4);
    int* bsum     = (int*)alloc(1024 * 4);
    int* edge_src = (int*)alloc((size_t)E * 4);
    float* inv_deg = (float*)alloc((size_t)n * 4);
    float* agg0    = (float*)alloc((size_t)n * 5 * 4);
    unsigned short* Acat = (unsigned short*)alloc((size_t)n * 256 * 2);  // [agg1 | h1] bf16
    unsigned short* h2b  = (unsigned short*)alloc((size_t)n * 128 * 2);
    unsigned short* WT   = (unsigned short*)alloc((size_t)128 * 256 * 2);
    float* actor_s = (float*)alloc((size_t)n * 4);
    float* critic_v= (float*)alloc((size_t)n * 4);
    float* wcomb   = (float*)alloc(260 * 4);
    float* scalars = (float*)alloc(16);

    hipMemsetAsync(deg, 0, (size_t)n * 4, stream);

    const int nbE = (E + 255) / 256;
    const int nbN = (n + 255) / 256;
    const int nbScan = (n + SCAN_B - 1) / SCAN_B;

    k_count<<<nbE, 256, 0, stream>>>(ei, deg, E);
    k_blocksum<<<nbScan, SCAN_B, 0, stream>>>(deg, bsum, n);
    k_scan_bsum<<<1, 1024, 0, stream>>>(bsum, nbScan);
    k_scan_final<<<nbScan, SCAN_B, 0, stream>>>(deg, bsum, row_ptr, fill_pos, inv_deg, n);
    k_fill<<<nbE, 256, 0, stream>>>(ei, fill_pos, edge_src, E);

    k_agg0<<<nbN, 256, 0, stream>>>(x, row_ptr, edge_src, inv_deg, agg0, n);
    k_h1<<<(n + 1) / 2, dim3(128, 2), 0, stream>>>(x, agg0, Wl1, bl1, Wr1, Acat, n);

    k_agg128<<<(n + 3) / 4, dim3(64, 4), 0, stream>>>(Acat, row_ptr, edge_src, inv_deg, n);

    k_prepw<<<128, 256, 0, stream>>>(Wl2, Wr2, WT);
    k_h2_mfma<<<(n + 63) / 64, 256, 0, stream>>>(Acat, WT, bl2, h2b, n);

    k_prep<<<1, 128, 0, stream>>>(Wlc, blc, Wrc, Wf, bf, wcomb);
    k_heads<<<(n + 3) / 4, dim3(64, 4), 0, stream>>>(h2b, row_ptr, edge_src, inv_deg, x,
                                                     Wla, bla, Wra, wcomb, actor_s, critic_v, n);
    k_reduce<<<1, 1024, 0, stream>>>(actor_s, critic_v, scalars, out, n);
    k_final<<<nbN, 256, 0, stream>>>(actor_s, scalars, out, n);
}

// Round 3
// 294.036 us; speedup vs baseline: 1.5286x; 1.2287x over previous
//
#include <hip/hip_runtime.h>
#include <cmath>

// n=50000 nodes, E=800000 edges, F=128 units, IN_F=5.
// Output: x_actor[n] (log_softmax) then x_critic[1] -> out_size = n+1 floats.
//
// Pipeline (bf16 hidden path, scalarized heads):
//  CSR build (count/scan/fill)
//  agg0 (5-dim mean), h1 = tanh(...) -> bf16 into Acat[:,128:256]
//  agg128: gather bf16 h1, mean -> bf16 into Acat[:,0:128]
//  h2 tile = tanh([agg1|h1] @ [Wl2;Wr2] + bl2) via MFMA bf16, fused epilogue:
//    pa=h2.Wla, pc=h2.(Wlc@Wf), ra=h2.Wra, rc=h2.(Wrc@Wf)  (h2 never stored)
//  sagg: per-node scalar gather of (pa,pc) over edges (L2-resident, 8B/edge)
//  reduce: logsumexp + critic mean/tanh; final: subtract lse

#define SCAN_B 256

typedef short short8 __attribute__((ext_vector_type(8)));
typedef float f32x4 __attribute__((ext_vector_type(4)));

__device__ __forceinline__ unsigned short f2b(float f) {
    union { float f; unsigned int u; } v; v.f = f;
    unsigned int r = (v.u + 0x7FFFu + ((v.u >> 16) & 1u)) >> 16;
    return (unsigned short)r;
}
__device__ __forceinline__ float b2f_lo(unsigned int u) {
    union { unsigned int u; float f; } v; v.u = u << 16; return v.f;
}
__device__ __forceinline__ float b2f_hi(unsigned int u) {
    union { unsigned int u; float f; } v; v.u = u & 0xFFFF0000u; return v.f;
}

__global__ void k_count(const int* __restrict__ ei, int* __restrict__ deg, int E) {
    int e = blockIdx.x * 256 + threadIdx.x;
    if (e >= E) return;
    atomicAdd(&deg[ei[E + e]], 1);
}

__global__ void k_blocksum(const int* __restrict__ deg, int* __restrict__ bsum, int n) {
    __shared__ int sd[SCAN_B];
    int i = blockIdx.x * SCAN_B + threadIdx.x;
    sd[threadIdx.x] = (i < n) ? deg[i] : 0;
    __syncthreads();
    for (int s = SCAN_B / 2; s > 0; s >>= 1) {
        if (threadIdx.x < s) sd[threadIdx.x] += sd[threadIdx.x + s];
        __syncthreads();
    }
    if (threadIdx.x == 0) bsum[blockIdx.x] = sd[0];
}

__global__ void k_scan_bsum(int* __restrict__ bsum, int nb) {
    __shared__ int sd[1024];
    int t = threadIdx.x;
    int v = (t < nb) ? bsum[t] : 0;
    sd[t] = v;
    __syncthreads();
    for (int off = 1; off < 1024; off <<= 1) {
        int add = (t >= off) ? sd[t - off] : 0;
        __syncthreads();
        sd[t] += add;
        __syncthreads();
    }
    if (t < nb) bsum[t] = sd[t] - v;
}

__global__ void k_scan_final(const int* __restrict__ deg, const int* __restrict__ bsum,
                             int* __restrict__ row_ptr, int* __restrict__ fill_pos,
                             float* __restrict__ inv_deg, int n) {
    __shared__ int sd[SCAN_B];
    int t = threadIdx.x;
    int i = blockIdx.x * SCAN_B + t;
    int v = (i < n) ? deg[i] : 0;
    sd[t] = v;
    __syncthreads();
    for (int off = 1; off < SCAN_B; off <<= 1) {
        int add = (t >= off) ? sd[t - off] : 0;
        __syncthreads();
        sd[t] += add;
        __syncthreads();
    }
    if (i < n) {
        int excl = bsum[blockIdx.x] + sd[t] - v;
        row_ptr[i] = excl;
        fill_pos[i] = excl;
        inv_deg[i] = 1.0f / fmaxf((float)v, 1.0f);
        if (i == n - 1) row_ptr[n] = excl + v;
    }
}

__global__ void k_fill(const int* __restrict__ ei, int* __restrict__ fill_pos,
                       int* __restrict__ edge_src, int E) {
    int e = blockIdx.x * 256 + threadIdx.x;
    if (e >= E) return;
    int src = ei[e];
    int dst = ei[E + e];
    int pos = atomicAdd(&fill_pos[dst], 1);
    edge_src[pos] = src;
}

__global__ void k_agg0(const float* __restrict__ x, const int* __restrict__ row_ptr,
                       const int* __restrict__ edge_src, const float* __restrict__ inv_deg,
                       float* __restrict__ agg0, int n) {
    int i = blockIdx.x * 256 + threadIdx.x;
    if (i >= n) return;
    float a0 = 0, a1 = 0, a2 = 0, a3 = 0, a4 = 0;
    int s = row_ptr[i], e = row_ptr[i + 1];
    for (int t = s; t < e; ++t) {
        const float* xp = x + (size_t)edge_src[t] * 5;
        a0 += xp[0]; a1 += xp[1]; a2 += xp[2]; a3 += xp[3]; a4 += xp[4];
    }
    float iv = inv_deg[i];
    float* o = agg0 + (size_t)i * 5;
    o[0] = a0 * iv; o[1] = a1 * iv; o[2] = a2 * iv; o[3] = a3 * iv; o[4] = a4 * iv;
}

// h1[i,j] = tanh(agg0[i,:]@Wl1[:,j] + bl1[j] + x[i,:]@Wr1[:,j]) -> bf16 into Acat[:,128+j]
__global__ void k_h1(const float* __restrict__ x, const float* __restrict__ agg0,
                     const float* __restrict__ Wl1, const float* __restrict__ bl1,
                     const float* __restrict__ Wr1, unsigned short* __restrict__ Acat, int n) {
    __shared__ float sA[2][5], sX[2][5];
    int node = blockIdx.x * 2 + threadIdx.y;
    int j = threadIdx.x;
    if (node < n && j < 5) {
        sA[threadIdx.y][j] = agg0[(size_t)node * 5 + j];
        sX[threadIdx.y][j] = x[(size_t)node * 5 + j];
    }
    __syncthreads();
    if (node >= n) return;
    float acc = bl1[j];
#pragma unroll
    for (int k = 0; k < 5; k++)
        acc += sA[threadIdx.y][k] * Wl1[k * 128 + j] + sX[threadIdx.y][k] * Wr1[k * 128 + j];
    Acat[(size_t)node * 256 + 128 + j] = f2b(tanhf(acc));
}

// wave-per-node bf16 mean aggregation of h1 (Acat cols 128:256) -> Acat cols 0:128
__global__ void k_agg128(unsigned short* __restrict__ Acat, const int* __restrict__ row_ptr,
                         const int* __restrict__ edge_src, const float* __restrict__ inv_deg,
                         int n) {
    int node = blockIdx.x * 4 + threadIdx.y;
    if (node >= n) return;
    int lane = threadIdx.x;
    int s = row_ptr[node], e = row_ptr[node + 1];
    float ax = 0.f, ay = 0.f;
    for (int t = s; t < e; ++t) {
        int src = edge_src[t];
        unsigned int u = ((const unsigned int*)(Acat + (size_t)src * 256 + 128))[lane];
        ax += b2f_lo(u);
        ay += b2f_hi(u);
    }
    float iv = inv_deg[node];
    unsigned int out = (unsigned int)f2b(ax * iv) | ((unsigned int)f2b(ay * iv) << 16);
    ((unsigned int*)(Acat + (size_t)node * 256))[lane] = out;
}

// WT[j][k] = bf16( k<128 ? Wl2[k][j] : Wr2[k-128][j] )  -- 128x256
__global__ void k_prepw(const float* __restrict__ Wl2, const float* __restrict__ Wr2,
                        unsigned short* __restrict__ WT) {
    int j = blockIdx.x;
    int k = threadIdx.x;
    float v = (k < 128) ? Wl2[(size_t)k * 128 + j] : Wr2[(size_t)(k - 128) * 128 + j];
    WT[(size_t)j * 256 + k] = f2b(v);
}

// wcomb[0:128]=Wlc@Wf, wcomb[128:256]=Wrc@Wf, wcomb[256]=blc.Wf+bf
__global__ void k_prep(const float* __restrict__ Wlc, const float* __restrict__ blc,
                       const float* __restrict__ Wrc, const float* __restrict__ Wf,
                       const float* __restrict__ bf, float* __restrict__ wcomb) {
    int k = threadIdx.x;
    float sl = 0.f, sr = 0.f;
    for (int j = 0; j < 128; j++) {
        float wf = Wf[j];
        sl += Wlc[(size_t)k * 128 + j] * wf;
        sr += Wrc[(size_t)k * 128 + j] * wf;
    }
    wcomb[k] = sl;
    wcomb[128 + k] = sr;
    __shared__ float sd[128];
    sd[k] = blc[k] * Wf[k];
    __syncthreads();
    for (int s = 64; s > 0; s >>= 1) {
        if (k < s) sd[k] += sd[k + s];
        __syncthreads();
    }
    if (k == 0) wcomb[256] = sd[0] + bf[0];
}

// h2 tile = tanh(Acat[n,256] @ WT^T + bl2) via MFMA 16x16x32 bf16, then fused
// head dots: pp[i]=(h2.Wla, h2.wcomb_l), self[i]=(h2.Wra, h2.wcomb_r). h2 not stored.
// block 256 = 4 waves; block tile 64 rows; wave tile 16 rows x 128 cols.
__global__ void k_h2_mfma_dots(const unsigned short* __restrict__ Acat,
                               const unsigned short* __restrict__ WT,
                               const float* __restrict__ bl2,
                               const float* __restrict__ Wla,
                               const float* __restrict__ Wra,
                               const float* __restrict__ wcomb,
                               float2* __restrict__ pp, float2* __restrict__ self, int n) {
    int wave = threadIdx.x >> 6;
    int lane = threadIdx.x & 63;
    int r = lane & 15;   // A row-in-tile / B,D col-in-tile
    int g = lane >> 4;   // k-group / D row-group
    int rowbase = blockIdx.x * 64 + wave * 16;
    int arow = rowbase + r;
    if (arow > n - 1) arow = n - 1;

    short8 a[8];
    const short* ap = (const short*)(Acat + (size_t)arow * 256 + g * 8);
#pragma unroll
    for (int kk = 0; kk < 8; kk++)
        a[kk] = *(const short8*)(ap + kk * 32);

    float ppa[4] = {0, 0, 0, 0}, ppc[4] = {0, 0, 0, 0};
    float pra[4] = {0, 0, 0, 0}, prc[4] = {0, 0, 0, 0};

#pragma unroll
    for (int nt = 0; nt < 8; nt++) {
        f32x4 acc = {0.f, 0.f, 0.f, 0.f};
        const short* bp = (const short*)(WT + (size_t)(nt * 16 + r) * 256 + g * 8);
#pragma unroll
        for (int kk = 0; kk < 8; kk++) {
            short8 b = *(const short8*)(bp + kk * 32);
            acc = __builtin_amdgcn_mfma_f32_16x16x32_bf16(a[kk], b, acc, 0, 0, 0);
        }
        int col = nt * 16 + r;  // D: col=lane&15, row=4*(lane>>4)+q
        float bj  = bl2[col];
        float wa  = Wla[col];
        float wra = Wra[col];
        float wcl = wcomb[col];
        float wcr = wcomb[128 + col];
#pragma unroll
        for (int q = 0; q < 4; q++) {
            float t = tanhf(acc[q] + bj);
            ppa[q] += t * wa;
            ppc[q] += t * wcl;
            pra[q] += t * wra;
            prc[q] += t * wcr;
        }
    }
    // reduce over the 16 lanes (r) within each k-group g; masks <16 stay in-group
#pragma unroll
    for (int q = 0; q < 4; q++) {
#pragma unroll
        for (int off = 8; off >= 1; off >>= 1) {
            ppa[q] += __shfl_xor(ppa[q], off);
            ppc[q] += __shfl_xor(ppc[q], off);
            pra[q] += __shfl_xor(pra[q], off);
            prc[q] += __shfl_xor(prc[q], off);
        }
    }
    if (r == 0) {
#pragma unroll
        for (int q = 0; q < 4; q++) {
            int rr = rowbase + g * 4 + q;
            if (rr < n) {
                pp[rr]   = make_float2(ppa[q], ppc[q]);
                self[rr] = make_float2(pra[q], prc[q]);
            }
        }
    }
}

// per-node scalar gather of (pa,pc); working set 400KB -> L2-resident.
__global__ void k_sagg(const float2* __restrict__ pp, const float2* __restrict__ self,
                       const int* __restrict__ row_ptr, const int* __restrict__ edge_src,
                       const float* __restrict__ inv_deg, const float* __restrict__ x,
                       const float* __restrict__ bla, const float* __restrict__ wcomb,
                       float* __restrict__ actor_s, float* __restrict__ critic_v, int n) {
    int i = blockIdx.x * 256 + threadIdx.x;
    if (i >= n) return;
    int s = row_ptr[i], e = row_ptr[i + 1];
    float sa = 0.f, sc = 0.f;
    for (int t = s; t < e; ++t) {
        float2 v = pp[edge_src[t]];
        sa += v.x; sc += v.y;
    }
    float iv = inv_deg[i];
    float2 sf = self[i];
    float a = sa * iv + sf.x + bla[0];
    if (x[(size_t)i * 5 + 2] != 0.0f) a = -INFINITY;
    actor_s[i] = a;
    critic_v[i] = sc * iv + sf.y + wcomb[256];
}

__global__ void k_reduce(const float* __restrict__ actor_s, const float* __restrict__ critic_v,
                         float* __restrict__ scalars, float* __restrict__ d_out, int n) {
    __shared__ float sm[1024], ss[1024], sc[1024];
    int t = threadIdx.x;
    float m = -INFINITY, sum = 0.f, cs = 0.f;
    for (int i = t; i < n; i += 1024) {
        cs += critic_v[i];
        float s = actor_s[i];
        if (s == -INFINITY) continue;
        if (s > m) {
            sum = sum * expf(m - s);
            m = s;
        }
        sum += expf(s - m);
    }
    sm[t] = m; ss[t] = sum; sc[t] = cs;
    __syncthreads();
    for (int s2 = 512; s2 > 0; s2 >>= 1) {
        if (t < s2) {
            float m2 = sm[t + s2], v2 = ss[t + s2];
            float M = fmaxf(sm[t], m2);
            if (M == -INFINITY) {
                ss[t] = 0.f;
            } else {
                ss[t] = ss[t] * expf(sm[t] - M) + v2 * expf(m2 - M);
            }
            sm[t] = M;
            sc[t] += sc[t + s2];
        }
        __syncthreads();
    }
    if (t == 0) {
        scalars[0] = sm[0] + logf(ss[0]);
        d_out[n] = tanhf(sc[0] / (float)n);
    }
}

__global__ void k_final(const float* __restrict__ actor_s, const float* __restrict__ scalars,
                        float* __restrict__ d_out, int n) {
    int i = blockIdx.x * 256 + threadIdx.x;
    if (i >= n) return;
    d_out[i] = actor_s[i] - scalars[0];
}

extern "C" void kernel_launch(void* const* d_in, const int* in_sizes, int n_in,
                              void* d_out, int out_size, void* d_ws, size_t ws_size,
                              hipStream_t stream) {
    const float* x   = (const float*)d_in[0];
    const int*   ei  = (const int*)d_in[1];
    const float* Wl1 = (const float*)d_in[3];
    const float* bl1 = (const float*)d_in[4];
    const float* Wr1 = (const float*)d_in[5];
    const float* Wl2 = (const float*)d_in[6];
    const float* bl2 = (const float*)d_in[7];
    const float* Wr2 = (const float*)d_in[8];
    const float* Wla = (const float*)d_in[9];
    const float* bla = (const float*)d_in[10];
    const float* Wra = (const float*)d_in[11];
    const float* Wlc = (const float*)d_in[12];
    const float* blc = (const float*)d_in[13];
    const float* Wrc = (const float*)d_in[14];
    const float* Wf  = (const float*)d_in[15];
    const float* bf  = (const float*)d_in[16];

    const int n = in_sizes[0] / 5;
    const int E = in_sizes[1] / 2;
    float* out = (float*)d_out;

    char* w = (char*)d_ws;
    auto alloc = [&](size_t bytes) -> void* {
        void* p = (void*)w;
        w += (bytes + 255) & ~(size_t)255;
        return p;
    };
    int* deg      = (int*)alloc((size_t)n * 4);
    int* row_ptr  = (int*)alloc((size_t)(n + 1) * 4);
    int* fill_pos = (int*)alloc((size_t)n * 4);
    int* bsum     = (int*)alloc(1024 * 4);
    int* edge_src = (int*)alloc((size_t)E * 4);
    float* inv_deg = (float*)alloc((size_t)n * 4);
    float* agg0    = (float*)alloc((size_t)n * 5 * 4);
    unsigned short* Acat = (unsigned short*)alloc((size_t)n * 256 * 2);  // [agg1 | h1] bf16
    unsigned short* WT   = (unsigned short*)alloc((size_t)128 * 256 * 2);
    float2* pp     = (float2*)alloc((size_t)n * 8);
    float2* selfb  = (float2*)alloc((size_t)n * 8);
    float* actor_s = (float*)alloc((size_t)n * 4);
    float* critic_v= (float*)alloc((size_t)n * 4);
    float* wcomb   = (float*)alloc(260 * 4);
    float* scalars = (float*)alloc(16);

    hipMemsetAsync(deg, 0, (size_t)n * 4, stream);

    const int nbE = (E + 255) / 256;
    const int nbN = (n + 255) / 256;
    const int nbScan = (n + SCAN_B - 1) / SCAN_B;

    k_count<<<nbE, 256, 0, stream>>>(ei, deg, E);
    k_blocksum<<<nbScan, SCAN_B, 0, stream>>>(deg, bsum, n);
    k_scan_bsum<<<1, 1024, 0, stream>>>(bsum, nbScan);
    k_scan_final<<<nbScan, SCAN_B, 0, stream>>>(deg, bsum, row_ptr, fill_pos, inv_deg, n);
    k_fill<<<nbE, 256, 0, stream>>>(ei, fill_pos, edge_src, E);

    k_agg0<<<nbN, 256, 0, stream>>>(x, row_ptr, edge_src, inv_deg, agg0, n);
    k_h1<<<(n + 1) / 2, dim3(128, 2), 0, stream>>>(x, agg0, Wl1, bl1, Wr1, Acat, n);

    k_agg128<<<(n + 3) / 4, dim3(64, 4), 0, stream>>>(Acat, row_ptr, edge_src, inv_deg, n);

    k_prepw<<<128, 256, 0, stream>>>(Wl2, Wr2, WT);
    k_prep<<<1, 128, 0, stream>>>(Wlc, blc, Wrc, Wf, bf, wcomb);
    k_h2_mfma_dots<<<(n + 63) / 64, 256, 0, stream>>>(Acat, WT, bl2, Wla, Wra, wcomb,
                                                      pp, selfb, n);

    k_sagg<<<nbN, 256, 0, stream>>>(pp, selfb, row_ptr, edge_src, inv_deg, x,
                                    bla, wcomb, actor_s, critic_v, n);
    k_reduce<<<1, 1024, 0, stream>>>(actor_s, critic_v, scalars, out, n);
    k_final<<<nbN, 256, 0, stream>>>(actor_s, scalars, out, n);
}

// Round 4
// 254.674 us; speedup vs baseline: 1.7649x; 1.1546x over previous
//
#include <hip/hip_runtime.h>
#include <cmath>

// n=50000 nodes, E=800000 edges, F=128 units, IN_F=5.
// Output: x_actor[n] (log_softmax) then x_critic[1] -> out_size = n+1 floats.
//
// Pipeline:
//  CSR build (count/scan/fill)
//  agg0 (5-dim mean); h1 = tanh(...) -> bf16 into Acat[:,128:256] AND fp8 copy H1f8
//  aggc x2 (64-dim chunks): gather fp8 h1, mean -> bf16 into Acat[:,0:128]
//     (fp8 payload halves gather bytes; 3.2MB/chunk fits per-XCD L2)
//  h2 tile = tanh([agg1|h1] @ [Wl2;Wr2] + bl2) via MFMA bf16, fused epilogue
//    head dots (pa,pc,ra,rc); h2 never materialized
//  sagg: per-node scalar gather of (pa,pc) (L2-resident, 8B/edge)
//  reduce: logsumexp + critic mean/tanh; final: subtract lse

#define SCAN_B 256

typedef short short8 __attribute__((ext_vector_type(8)));
typedef float f32x4 __attribute__((ext_vector_type(4)));
typedef float f32x2 __attribute__((ext_vector_type(2)));

__device__ __forceinline__ unsigned short f2b(float f) {
    union { float f; unsigned int u; } v; v.f = f;
    unsigned int r = (v.u + 0x7FFFu + ((v.u >> 16) & 1u)) >> 16;
    return (unsigned short)r;
}
__device__ __forceinline__ float b2f_lo(unsigned int u) {
    union { unsigned int u; float f; } v; v.u = u << 16; return v.f;
}
__device__ __forceinline__ float b2f_hi(unsigned int u) {
    union { unsigned int u; float f; } v; v.u = u & 0xFFFF0000u; return v.f;
}

__global__ void k_count(const int* __restrict__ ei, int* __restrict__ deg, int E) {
    int e = blockIdx.x * 256 + threadIdx.x;
    if (e >= E) return;
    atomicAdd(&deg[ei[E + e]], 1);
}

__global__ void k_blocksum(const int* __restrict__ deg, int* __restrict__ bsum, int n) {
    __shared__ int sd[SCAN_B];
    int i = blockIdx.x * SCAN_B + threadIdx.x;
    sd[threadIdx.x] = (i < n) ? deg[i] : 0;
    __syncthreads();
    for (int s = SCAN_B / 2; s > 0; s >>= 1) {
        if (threadIdx.x < s) sd[threadIdx.x] += sd[threadIdx.x + s];
        __syncthreads();
    }
    if (threadIdx.x == 0) bsum[blockIdx.x] = sd[0];
}

__global__ void k_scan_bsum(int* __restrict__ bsum, int nb) {
    __shared__ int sd[1024];
    int t = threadIdx.x;
    int v = (t < nb) ? bsum[t] : 0;
    sd[t] = v;
    __syncthreads();
    for (int off = 1; off < 1024; off <<= 1) {
        int add = (t >= off) ? sd[t - off] : 0;
        __syncthreads();
        sd[t] += add;
        __syncthreads();
    }
    if (t < nb) bsum[t] = sd[t] - v;
}

__global__ void k_scan_final(const int* __restrict__ deg, const int* __restrict__ bsum,
                             int* __restrict__ row_ptr, int* __restrict__ fill_pos,
                             float* __restrict__ inv_deg, int n) {
    __shared__ int sd[SCAN_B];
    int t = threadIdx.x;
    int i = blockIdx.x * SCAN_B + t;
    int v = (i < n) ? deg[i] : 0;
    sd[t] = v;
    __syncthreads();
    for (int off = 1; off < SCAN_B; off <<= 1) {
        int add = (t >= off) ? sd[t - off] : 0;
        __syncthreads();
        sd[t] += add;
        __syncthreads();
    }
    if (i < n) {
        int excl = bsum[blockIdx.x] + sd[t] - v;
        row_ptr[i] = excl;
        fill_pos[i] = excl;
        inv_deg[i] = 1.0f / fmaxf((float)v, 1.0f);
        if (i == n - 1) row_ptr[n] = excl + v;
    }
}

__global__ void k_fill(const int* __restrict__ ei, int* __restrict__ fill_pos,
                       int* __restrict__ edge_src, int E) {
    int e = blockIdx.x * 256 + threadIdx.x;
    if (e >= E) return;
    int src = ei[e];
    int dst = ei[E + e];
    int pos = atomicAdd(&fill_pos[dst], 1);
    edge_src[pos] = src;
}

__global__ void k_agg0(const float* __restrict__ x, const int* __restrict__ row_ptr,
                       const int* __restrict__ edge_src, const float* __restrict__ inv_deg,
                       float* __restrict__ agg0, int n) {
    int i = blockIdx.x * 256 + threadIdx.x;
    if (i >= n) return;
    float a0 = 0, a1 = 0, a2 = 0, a3 = 0, a4 = 0;
    int s = row_ptr[i], e = row_ptr[i + 1];
    for (int t = s; t < e; ++t) {
        const float* xp = x + (size_t)edge_src[t] * 5;
        a0 += xp[0]; a1 += xp[1]; a2 += xp[2]; a3 += xp[3]; a4 += xp[4];
    }
    float iv = inv_deg[i];
    float* o = agg0 + (size_t)i * 5;
    o[0] = a0 * iv; o[1] = a1 * iv; o[2] = a2 * iv; o[3] = a3 * iv; o[4] = a4 * iv;
}

// h1[i,j] = tanh(agg0@Wl1 + bl1 + x@Wr1); writes bf16 (Acat[:,128:256]) + fp8 copy (H1f8u).
// block (32,8): 8 nodes/block, 4 cols/thread.
__global__ void k_h1(const float* __restrict__ x, const float* __restrict__ agg0,
                     const float* __restrict__ Wl1, const float* __restrict__ bl1,
                     const float* __restrict__ Wr1, unsigned short* __restrict__ Acat,
                     unsigned int* __restrict__ H1f8u, int n) {
    __shared__ float sA[8][5], sX[8][5];
    int ty = threadIdx.y, tx = threadIdx.x;
    int node = blockIdx.x * 8 + ty;
    if (node < n && tx < 5) {
        sA[ty][tx] = agg0[(size_t)node * 5 + tx];
        sX[ty][tx] = x[(size_t)node * 5 + tx];
    }
    __syncthreads();
    if (node >= n) return;
    int j0 = tx * 4;
    float4 acc = *(const float4*)(bl1 + j0);
#pragma unroll
    for (int k = 0; k < 5; k++) {
        float4 wl = *(const float4*)(Wl1 + k * 128 + j0);
        float4 wr = *(const float4*)(Wr1 + k * 128 + j0);
        float a = sA[ty][k], xx = sX[ty][k];
        acc.x += a * wl.x + xx * wr.x;
        acc.y += a * wl.y + xx * wr.y;
        acc.z += a * wl.z + xx * wr.z;
        acc.w += a * wl.w + xx * wr.w;
    }
    float t0 = tanhf(acc.x), t1 = tanhf(acc.y), t2 = tanhf(acc.z), t3 = tanhf(acc.w);
    uint2 bw;
    bw.x = (unsigned int)f2b(t0) | ((unsigned int)f2b(t1) << 16);
    bw.y = (unsigned int)f2b(t2) | ((unsigned int)f2b(t3) << 16);
    *(uint2*)(Acat + (size_t)node * 256 + 128 + j0) = bw;
    int p = __builtin_amdgcn_cvt_pk_fp8_f32(t0, t1, 0, false);
    p = __builtin_amdgcn_cvt_pk_fp8_f32(t2, t3, p, true);
    H1f8u[(size_t)node * 32 + tx] = (unsigned int)p;
}

// chunked fp8 mean-aggregation: chunk c covers dims [c*64, c*64+64).
// 16 lanes/node (each lane 4 dims), 16 nodes/block. Working set/chunk = 3.2MB (L2-fit).
__global__ void k_aggc(const unsigned int* __restrict__ H1f8u, const int* __restrict__ row_ptr,
                       const int* __restrict__ edge_src, const float* __restrict__ inv_deg,
                       unsigned short* __restrict__ Acat, int n, int c) {
    int tid = threadIdx.x;
    int grp = tid >> 4;
    int r = tid & 15;
    int node = blockIdx.x * 16 + grp;
    if (node >= n) return;
    int s = row_ptr[node], e = row_ptr[node + 1];
    const unsigned int* base = H1f8u + c * 16 + r;
    float s0 = 0.f, s1 = 0.f, s2 = 0.f, s3 = 0.f;
    int t = s;
    for (; t + 1 < e; t += 2) {
        unsigned int u0 = base[(size_t)edge_src[t] * 32];
        unsigned int u1 = base[(size_t)edge_src[t + 1] * 32];
        f32x2 lo = __builtin_amdgcn_cvt_pk_f32_fp8(u0, false);
        f32x2 hi = __builtin_amdgcn_cvt_pk_f32_fp8(u0, true);
        s0 += lo[0]; s1 += lo[1]; s2 += hi[0]; s3 += hi[1];
        lo = __builtin_amdgcn_cvt_pk_f32_fp8(u1, false);
        hi = __builtin_amdgcn_cvt_pk_f32_fp8(u1, true);
        s0 += lo[0]; s1 += lo[1]; s2 += hi[0]; s3 += hi[1];
    }
    if (t < e) {
        unsigned int u0 = base[(size_t)edge_src[t] * 32];
        f32x2 lo = __builtin_amdgcn_cvt_pk_f32_fp8(u0, false);
        f32x2 hi = __builtin_amdgcn_cvt_pk_f32_fp8(u0, true);
        s0 += lo[0]; s1 += lo[1]; s2 += hi[0]; s3 += hi[1];
    }
    float iv = inv_deg[node];
    uint2 w;
    w.x = (unsigned int)f2b(s0 * iv) | ((unsigned int)f2b(s1 * iv) << 16);
    w.y = (unsigned int)f2b(s2 * iv) | ((unsigned int)f2b(s3 * iv) << 16);
    *(uint2*)(Acat + (size_t)node * 256 + c * 64 + r * 4) = w;
}

// WT[j][k] = bf16( k<128 ? Wl2[k][j] : Wr2[k-128][j] )  -- 128x256
__global__ void k_prepw(const float* __restrict__ Wl2, const float* __restrict__ Wr2,
                        unsigned short* __restrict__ WT) {
    int j = blockIdx.x;
    int k = threadIdx.x;
    float v = (k < 128) ? Wl2[(size_t)k * 128 + j] : Wr2[(size_t)(k - 128) * 128 + j];
    WT[(size_t)j * 256 + k] = f2b(v);
}

// wcomb[0:128]=Wlc@Wf, wcomb[128:256]=Wrc@Wf, wcomb[256]=blc.Wf+bf
__global__ void k_prep(const float* __restrict__ Wlc, const float* __restrict__ blc,
                       const float* __restrict__ Wrc, const float* __restrict__ Wf,
                       const float* __restrict__ bf, float* __restrict__ wcomb) {
    int k = threadIdx.x;
    float sl = 0.f, sr = 0.f;
    for (int j = 0; j < 128; j++) {
        float wf = Wf[j];
        sl += Wlc[(size_t)k * 128 + j] * wf;
        sr += Wrc[(size_t)k * 128 + j] * wf;
    }
    wcomb[k] = sl;
    wcomb[128 + k] = sr;
    __shared__ float sd[128];
    sd[k] = blc[k] * Wf[k];
    __syncthreads();
    for (int s = 64; s > 0; s >>= 1) {
        if (k < s) sd[k] += sd[k + s];
        __syncthreads();
    }
    if (k == 0) wcomb[256] = sd[0] + bf[0];
}

// h2 tile = tanh(Acat[n,256] @ WT^T + bl2) via MFMA, fused head dots. h2 not stored.
__global__ void k_h2_mfma_dots(const unsigned short* __restrict__ Acat,
                               const unsigned short* __restrict__ WT,
                               const float* __restrict__ bl2,
                               const float* __restrict__ Wla,
                               const float* __restrict__ Wra,
                               const float* __restrict__ wcomb,
                               float2* __restrict__ pp, float2* __restrict__ self, int n) {
    int wave = threadIdx.x >> 6;
    int lane = threadIdx.x & 63;
    int r = lane & 15;
    int g = lane >> 4;
    int rowbase = blockIdx.x * 64 + wave * 16;
    int arow = rowbase + r;
    if (arow > n - 1) arow = n - 1;

    short8 a[8];
    const short* ap = (const short*)(Acat + (size_t)arow * 256 + g * 8);
#pragma unroll
    for (int kk = 0; kk < 8; kk++)
        a[kk] = *(const short8*)(ap + kk * 32);

    float ppa[4] = {0, 0, 0, 0}, ppc[4] = {0, 0, 0, 0};
    float pra[4] = {0, 0, 0, 0}, prc[4] = {0, 0, 0, 0};

#pragma unroll
    for (int nt = 0; nt < 8; nt++) {
        f32x4 acc = {0.f, 0.f, 0.f, 0.f};
        const short* bp = (const short*)(WT + (size_t)(nt * 16 + r) * 256 + g * 8);
#pragma unroll
        for (int kk = 0; kk < 8; kk++) {
            short8 b = *(const short8*)(bp + kk * 32);
            acc = __builtin_amdgcn_mfma_f32_16x16x32_bf16(a[kk], b, acc, 0, 0, 0);
        }
        int col = nt * 16 + r;
        float bj  = bl2[col];
        float wa  = Wla[col];
        float wra = Wra[col];
        float wcl = wcomb[col];
        float wcr = wcomb[128 + col];
#pragma unroll
        for (int q = 0; q < 4; q++) {
            float t = tanhf(acc[q] + bj);
            ppa[q] += t * wa;
            ppc[q] += t * wcl;
            pra[q] += t * wra;
            prc[q] += t * wcr;
        }
    }
#pragma unroll
    for (int q = 0; q < 4; q++) {
#pragma unroll
        for (int off = 8; off >= 1; off >>= 1) {
            ppa[q] += __shfl_xor(ppa[q], off);
            ppc[q] += __shfl_xor(ppc[q], off);
            pra[q] += __shfl_xor(pra[q], off);
            prc[q] += __shfl_xor(prc[q], off);
        }
    }
    if (r == 0) {
#pragma unroll
        for (int q = 0; q < 4; q++) {
            int rr = rowbase + g * 4 + q;
            if (rr < n) {
                pp[rr]   = make_float2(ppa[q], ppc[q]);
                self[rr] = make_float2(pra[q], prc[q]);
            }
        }
    }
}

__global__ void k_sagg(const float2* __restrict__ pp, const float2* __restrict__ self,
                       const int* __restrict__ row_ptr, const int* __restrict__ edge_src,
                       const float* __restrict__ inv_deg, const float* __restrict__ x,
                       const float* __restrict__ bla, const float* __restrict__ wcomb,
                       float* __restrict__ actor_s, float* __restrict__ critic_v, int n) {
    int i = blockIdx.x * 256 + threadIdx.x;
    if (i >= n) return;
    int s = row_ptr[i], e = row_ptr[i + 1];
    float sa = 0.f, sc = 0.f;
    for (int t = s; t < e; ++t) {
        float2 v = pp[edge_src[t]];
        sa += v.x; sc += v.y;
    }
    float iv = inv_deg[i];
    float2 sf = self[i];
    float a = sa * iv + sf.x + bla[0];
    if (x[(size_t)i * 5 + 2] != 0.0f) a = -INFINITY;
    actor_s[i] = a;
    critic_v[i] = sc * iv + sf.y + wcomb[256];
}

__global__ void k_reduce(const float* __restrict__ actor_s, const float* __restrict__ critic_v,
                         float* __restrict__ scalars, float* __restrict__ d_out, int n) {
    __shared__ float sm[1024], ss[1024], sc[1024];
    int t = threadIdx.x;
    float m = -INFINITY, sum = 0.f, cs = 0.f;
    for (int i = t; i < n; i += 1024) {
        cs += critic_v[i];
        float s = actor_s[i];
        if (s == -INFINITY) continue;
        if (s > m) {
            sum = sum * expf(m - s);
            m = s;
        }
        sum += expf(s - m);
    }
    sm[t] = m; ss[t] = sum; sc[t] = cs;
    __syncthreads();
    for (int s2 = 512; s2 > 0; s2 >>= 1) {
        if (t < s2) {
            float m2 = sm[t + s2], v2 = ss[t + s2];
            float M = fmaxf(sm[t], m2);
            if (M == -INFINITY) {
                ss[t] = 0.f;
            } else {
                ss[t] = ss[t] * expf(sm[t] - M) + v2 * expf(m2 - M);
            }
            sm[t] = M;
            sc[t] += sc[t + s2];
        }
        __syncthreads();
    }
    if (t == 0) {
        scalars[0] = sm[0] + logf(ss[0]);
        d_out[n] = tanhf(sc[0] / (float)n);
    }
}

__global__ void k_final(const float* __restrict__ actor_s, const float* __restrict__ scalars,
                        float* __restrict__ d_out, int n) {
    int i = blockIdx.x * 256 + threadIdx.x;
    if (i >= n) return;
    d_out[i] = actor_s[i] - scalars[0];
}

extern "C" void kernel_launch(void* const* d_in, const int* in_sizes, int n_in,
                              void* d_out, int out_size, void* d_ws, size_t ws_size,
                              hipStream_t stream) {
    const float* x   = (const float*)d_in[0];
    const int*   ei  = (const int*)d_in[1];
    const float* Wl1 = (const float*)d_in[3];
    const float* bl1 = (const float*)d_in[4];
    const float* Wr1 = (const float*)d_in[5];
    const float* Wl2 = (const float*)d_in[6];
    const float* bl2 = (const float*)d_in[7];
    const float* Wr2 = (const float*)d_in[8];
    const float* Wla = (const float*)d_in[9];
    const float* bla = (const float*)d_in[10];
    const float* Wra = (const float*)d_in[11];
    const float* Wlc = (const float*)d_in[12];
    const float* blc = (const float*)d_in[13];
    const float* Wrc = (const float*)d_in[14];
    const float* Wf  = (const float*)d_in[15];
    const float* bf  = (const float*)d_in[16];

    const int n = in_sizes[0] / 5;
    const int E = in_sizes[1] / 2;
    float* out = (float*)d_out;

    char* w = (char*)d_ws;
    auto alloc = [&](size_t bytes) -> void* {
        void* p = (void*)w;
        w += (bytes + 255) & ~(size_t)255;
        return p;
    };
    int* deg      = (int*)alloc((size_t)n * 4);
    int* row_ptr  = (int*)alloc((size_t)(n + 1) * 4);
    int* fill_pos = (int*)alloc((size_t)n * 4);
    int* bsum     = (int*)alloc(1024 * 4);
    int* edge_src = (int*)alloc((size_t)E * 4);
    float* inv_deg = (float*)alloc((size_t)n * 4);
    float* agg0    = (float*)alloc((size_t)n * 5 * 4);
    unsigned short* Acat = (unsigned short*)alloc((size_t)n * 256 * 2);  // [agg1 | h1] bf16
    unsigned int* H1f8u  = (unsigned int*)alloc((size_t)n * 128);       // h1 fp8 copy
    unsigned short* WT   = (unsigned short*)alloc((size_t)128 * 256 * 2);
    float2* pp     = (float2*)alloc((size_t)n * 8);
    float2* selfb  = (float2*)alloc((size_t)n * 8);
    float* actor_s = (float*)alloc((size_t)n * 4);
    float* critic_v= (float*)alloc((size_t)n * 4);
    float* wcomb   = (float*)alloc(260 * 4);
    float* scalars = (float*)alloc(16);

    hipMemsetAsync(deg, 0, (size_t)n * 4, stream);

    const int nbE = (E + 255) / 256;
    const int nbN = (n + 255) / 256;
    const int nbScan = (n + SCAN_B - 1) / SCAN_B;

    k_count<<<nbE, 256, 0, stream>>>(ei, deg, E);
    k_blocksum<<<nbScan, SCAN_B, 0, stream>>>(deg, bsum, n);
    k_scan_bsum<<<1, 1024, 0, stream>>>(bsum, nbScan);
    k_scan_final<<<nbScan, SCAN_B, 0, stream>>>(deg, bsum, row_ptr, fill_pos, inv_deg, n);
    k_fill<<<nbE, 256, 0, stream>>>(ei, fill_pos, edge_src, E);

    k_agg0<<<nbN, 256, 0, stream>>>(x, row_ptr, edge_src, inv_deg, agg0, n);
    k_h1<<<(n + 7) / 8, dim3(32, 8), 0, stream>>>(x, agg0, Wl1, bl1, Wr1, Acat, H1f8u, n);

    k_aggc<<<(n + 15) / 16, 256, 0, stream>>>(H1f8u, row_ptr, edge_src, inv_deg, Acat, n, 0);
    k_aggc<<<(n + 15) / 16, 256, 0, stream>>>(H1f8u, row_ptr, edge_src, inv_deg, Acat, n, 1);

    k_prepw<<<128, 256, 0, stream>>>(Wl2, Wr2, WT);
    k_prep<<<1, 128, 0, stream>>>(Wlc, blc, Wrc, Wf, bf, wcomb);
    k_h2_mfma_dots<<<(n + 63) / 64, 256, 0, stream>>>(Acat, WT, bl2, Wla, Wra, wcomb,
                                                      pp, selfb, n);

    k_sagg<<<nbN, 256, 0, stream>>>(pp, selfb, row_ptr, edge_src, inv_deg, x,
                                    bla, wcomb, actor_s, critic_v, n);
    k_reduce<<<1, 1024, 0, stream>>>(actor_s, critic_v, scalars, out, n);
    k_final<<<nbN, 256, 0, stream>>>(actor_s, scalars, out, n);
}

// Round 5
// 212.713 us; speedup vs baseline: 2.1130x; 1.1973x over previous
//
#include <hip/hip_runtime.h>
#include <cmath>

// n=50000 nodes, E=800000 edges, F=128 units, IN_F=5.
// Output: x_actor[n] (log_softmax) then x_critic[1] -> out_size = n+1 floats.
//
// Pipeline:
//  bucketed CSR build: hist -> scan -> bin(chunked, LDS-staged) -> per-bucket csr
//  agg0 (5-dim mean); h1 = tanh(...) -> bf16 into Acat[:,128:256] AND fp8 copy H1f8
//  aggc x2 (64-dim chunks): gather fp8 h1, mean -> bf16 into Acat[:,0:128]
//  h2 tile = tanh([agg1|h1] @ [Wl2;Wr2] + bl2) via MFMA bf16, fused epilogue
//    head dots (pa,pc,ra,rc); h2 never materialized
//  sagg: per-node scalar gather of (pa,pc) (L2-resident, 8B/edge)
//  reduce: logsumexp + critic mean/tanh; final: subtract lse

#define NPB_SHIFT 7
#define NPB 128          // nodes per bucket
#define MAXNB 512        // max buckets supported (n <= 65536)
#define HBLK 192         // histogram blocks
#define CHUNK 8192       // edges per bin-scatter block

typedef short short8 __attribute__((ext_vector_type(8)));
typedef float f32x4 __attribute__((ext_vector_type(4)));
typedef float f32x2 __attribute__((ext_vector_type(2)));

__device__ __forceinline__ unsigned short f2b(float f) {
    union { float f; unsigned int u; } v; v.f = f;
    unsigned int r = (v.u + 0x7FFFu + ((v.u >> 16) & 1u)) >> 16;
    return (unsigned short)r;
}

// ---------------- bucketed CSR build ----------------

// per-block LDS histogram of dst>>7 -> partial[bucket*HBLK + blk]
__global__ void kb_hist(const int* __restrict__ ei, int* __restrict__ partial, int E, int NB) {
    __shared__ int h[MAXNB];
    for (int i = threadIdx.x; i < NB; i += 256) h[i] = 0;
    __syncthreads();
    for (int i = blockIdx.x * 256 + threadIdx.x; i < E; i += 256 * gridDim.x)
        atomicAdd(&h[ei[E + i] >> NPB_SHIFT], 1);
    __syncthreads();
    for (int b = threadIdx.x; b < NB; b += 256)
        partial[(size_t)b * HBLK + blockIdx.x] = h[b];
}

// single block MAXNB threads: sum partials per bucket, exclusive scan -> bucket_base, init cursors
__global__ void kb_scan(const int* __restrict__ partial, int* __restrict__ bucket_base,
                        int* __restrict__ bucket_cur, int NB) {
    __shared__ int sd[MAXNB];
    int t = threadIdx.x;
    int c = 0;
    if (t < NB) {
        const int* p = partial + (size_t)t * HBLK;
        for (int k = 0; k < HBLK; k++) c += p[k];
    }
    sd[t] = c;
    __syncthreads();
    for (int off = 1; off < MAXNB; off <<= 1) {
        int add = (t >= off) ? sd[t - off] : 0;
        __syncthreads();
        sd[t] += add;
        __syncthreads();
    }
    if (t < NB) {
        int excl = sd[t] - c;
        bucket_base[t] = excl;
        bucket_cur[t] = excl;
        if (t == NB - 1) bucket_base[NB] = sd[t];
    }
}

// chunked scatter into bucket regions; packed u32 = (ldst<<25) | src
__global__ void kb_bin(const int* __restrict__ ei, int* __restrict__ bucket_cur,
                       unsigned int* __restrict__ binned, int E, int NB) {
    __shared__ int lcnt[MAXNB];
    __shared__ int lbase[MAXNB];
    __shared__ int lcur[MAXNB];
    int s = blockIdx.x * CHUNK;
    int e = min(E, s + CHUNK);
    for (int i = threadIdx.x; i < NB; i += 256) lcnt[i] = 0;
    __syncthreads();
    for (int i = s + threadIdx.x; i < e; i += 256)
        atomicAdd(&lcnt[ei[E + i] >> NPB_SHIFT], 1);
    __syncthreads();
    for (int b = threadIdx.x; b < NB; b += 256) {
        int c = lcnt[b];
        lbase[b] = c ? atomicAdd(&bucket_cur[b], c) : 0;
        lcur[b] = 0;
    }
    __syncthreads();
    for (int i = s + threadIdx.x; i < e; i += 256) {
        int src = ei[i];
        int dst = ei[E + i];
        int b = dst >> NPB_SHIFT;
        int pos = lbase[b] + atomicAdd(&lcur[b], 1);
        binned[pos] = (unsigned int)src | ((unsigned int)(dst & (NPB - 1)) << 25);
    }
}

// one block (NPB threads) per bucket: local count+scan -> row_ptr/inv_deg, place edge_src
__global__ void kb_csr(const unsigned int* __restrict__ binned, const int* __restrict__ bucket_base,
                       int* __restrict__ row_ptr, float* __restrict__ inv_deg,
                       int* __restrict__ edge_src, int n, int NB) {
    __shared__ int lcnt[NPB];
    __shared__ int lexcl[NPB];
    __shared__ int lcur[NPB];
    int b = blockIdx.x;
    int t = threadIdx.x;
    int base = bucket_base[b], end = bucket_base[b + 1];
    lcnt[t] = 0;
    lcur[t] = 0;
    __syncthreads();
    for (int i = base + t; i < end; i += NPB)
        atomicAdd(&lcnt[binned[i] >> 25], 1);
    __syncthreads();
    int v = lcnt[t];
    lexcl[t] = v;
    __syncthreads();
    for (int off = 1; off < NPB; off <<= 1) {
        int add = (t >= off) ? lexcl[t - off] : 0;
        __syncthreads();
        lexcl[t] += add;
        __syncthreads();
    }
    int excl = lexcl[t] - v;
    __syncthreads();
    lexcl[t] = excl;
    __syncthreads();
    int node = b * NPB + t;
    if (node < n) {
        row_ptr[node] = base + excl;
        inv_deg[node] = 1.0f / fmaxf((float)v, 1.0f);
    }
    if (b == 0 && t == 0) row_ptr[n] = bucket_base[NB];
    for (int i = base + t; i < end; i += NPB) {
        unsigned int u = binned[i];
        int l = u >> 25;
        int pos = lexcl[l] + atomicAdd(&lcur[l], 1);
        edge_src[base + pos] = (int)(u & 0x01FFFFFFu);
    }
}

// ---------------- model ----------------

__global__ void k_agg0(const float* __restrict__ x, const int* __restrict__ row_ptr,
                       const int* __restrict__ edge_src, const float* __restrict__ inv_deg,
                       float* __restrict__ agg0, int n) {
    int i = blockIdx.x * 256 + threadIdx.x;
    if (i >= n) return;
    float a0 = 0, a1 = 0, a2 = 0, a3 = 0, a4 = 0;
    int s = row_ptr[i], e = row_ptr[i + 1];
    for (int t = s; t < e; ++t) {
        const float* xp = x + (size_t)edge_src[t] * 5;
        a0 += xp[0]; a1 += xp[1]; a2 += xp[2]; a3 += xp[3]; a4 += xp[4];
    }
    float iv = inv_deg[i];
    float* o = agg0 + (size_t)i * 5;
    o[0] = a0 * iv; o[1] = a1 * iv; o[2] = a2 * iv; o[3] = a3 * iv; o[4] = a4 * iv;
}

// h1[i,j] = tanh(agg0@Wl1 + bl1 + x@Wr1); writes bf16 (Acat[:,128:256]) + fp8 copy (H1f8u).
__global__ void k_h1(const float* __restrict__ x, const float* __restrict__ agg0,
                     const float* __restrict__ Wl1, const float* __restrict__ bl1,
                     const float* __restrict__ Wr1, unsigned short* __restrict__ Acat,
                     unsigned int* __restrict__ H1f8u, int n) {
    __shared__ float sA[8][5], sX[8][5];
    int ty = threadIdx.y, tx = threadIdx.x;
    int node = blockIdx.x * 8 + ty;
    if (node < n && tx < 5) {
        sA[ty][tx] = agg0[(size_t)node * 5 + tx];
        sX[ty][tx] = x[(size_t)node * 5 + tx];
    }
    __syncthreads();
    if (node >= n) return;
    int j0 = tx * 4;
    float4 acc = *(const float4*)(bl1 + j0);
#pragma unroll
    for (int k = 0; k < 5; k++) {
        float4 wl = *(const float4*)(Wl1 + k * 128 + j0);
        float4 wr = *(const float4*)(Wr1 + k * 128 + j0);
        float a = sA[ty][k], xx = sX[ty][k];
        acc.x += a * wl.x + xx * wr.x;
        acc.y += a * wl.y + xx * wr.y;
        acc.z += a * wl.z + xx * wr.z;
        acc.w += a * wl.w + xx * wr.w;
    }
    float t0 = tanhf(acc.x), t1 = tanhf(acc.y), t2 = tanhf(acc.z), t3 = tanhf(acc.w);
    uint2 bw;
    bw.x = (unsigned int)f2b(t0) | ((unsigned int)f2b(t1) << 16);
    bw.y = (unsigned int)f2b(t2) | ((unsigned int)f2b(t3) << 16);
    *(uint2*)(Acat + (size_t)node * 256 + 128 + j0) = bw;
    int p = __builtin_amdgcn_cvt_pk_fp8_f32(t0, t1, 0, false);
    p = __builtin_amdgcn_cvt_pk_fp8_f32(t2, t3, p, true);
    H1f8u[(size_t)node * 32 + tx] = (unsigned int)p;
}

// chunked fp8 mean-aggregation: chunk c covers dims [c*64, c*64+64).
__global__ void k_aggc(const unsigned int* __restrict__ H1f8u, const int* __restrict__ row_ptr,
                       const int* __restrict__ edge_src, const float* __restrict__ inv_deg,
                       unsigned short* __restrict__ Acat, int n, int c) {
    int tid = threadIdx.x;
    int grp = tid >> 4;
    int r = tid & 15;
    int node = blockIdx.x * 16 + grp;
    if (node >= n) return;
    int s = row_ptr[node], e = row_ptr[node + 1];
    const unsigned int* base = H1f8u + c * 16 + r;
    float s0 = 0.f, s1 = 0.f, s2 = 0.f, s3 = 0.f;
    int t = s;
    for (; t + 1 < e; t += 2) {
        unsigned int u0 = base[(size_t)edge_src[t] * 32];
        unsigned int u1 = base[(size_t)edge_src[t + 1] * 32];
        f32x2 lo = __builtin_amdgcn_cvt_pk_f32_fp8(u0, false);
        f32x2 hi = __builtin_amdgcn_cvt_pk_f32_fp8(u0, true);
        s0 += lo[0]; s1 += lo[1]; s2 += hi[0]; s3 += hi[1];
        lo = __builtin_amdgcn_cvt_pk_f32_fp8(u1, false);
        hi = __builtin_amdgcn_cvt_pk_f32_fp8(u1, true);
        s0 += lo[0]; s1 += lo[1]; s2 += hi[0]; s3 += hi[1];
    }
    if (t < e) {
        unsigned int u0 = base[(size_t)edge_src[t] * 32];
        f32x2 lo = __builtin_amdgcn_cvt_pk_f32_fp8(u0, false);
        f32x2 hi = __builtin_amdgcn_cvt_pk_f32_fp8(u0, true);
        s0 += lo[0]; s1 += lo[1]; s2 += hi[0]; s3 += hi[1];
    }
    float iv = inv_deg[node];
    uint2 w;
    w.x = (unsigned int)f2b(s0 * iv) | ((unsigned int)f2b(s1 * iv) << 16);
    w.y = (unsigned int)f2b(s2 * iv) | ((unsigned int)f2b(s3 * iv) << 16);
    *(uint2*)(Acat + (size_t)node * 256 + c * 64 + r * 4) = w;
}

// WT[j][k] = bf16( k<128 ? Wl2[k][j] : Wr2[k-128][j] )  -- 128x256
__global__ void k_prepw(const float* __restrict__ Wl2, const float* __restrict__ Wr2,
                        unsigned short* __restrict__ WT) {
    int j = blockIdx.x;
    int k = threadIdx.x;
    float v = (k < 128) ? Wl2[(size_t)k * 128 + j] : Wr2[(size_t)(k - 128) * 128 + j];
    WT[(size_t)j * 256 + k] = f2b(v);
}

// wcomb[0:128]=Wlc@Wf, wcomb[128:256]=Wrc@Wf, wcomb[256]=blc.Wf+bf
__global__ void k_prep(const float* __restrict__ Wlc, const float* __restrict__ blc,
                       const float* __restrict__ Wrc, const float* __restrict__ Wf,
                       const float* __restrict__ bf, float* __restrict__ wcomb) {
    int k = threadIdx.x;
    float sl = 0.f, sr = 0.f;
    for (int j = 0; j < 128; j++) {
        float wf = Wf[j];
        sl += Wlc[(size_t)k * 128 + j] * wf;
        sr += Wrc[(size_t)k * 128 + j] * wf;
    }
    wcomb[k] = sl;
    wcomb[128 + k] = sr;
    __shared__ float sd[128];
    sd[k] = blc[k] * Wf[k];
    __syncthreads();
    for (int s = 64; s > 0; s >>= 1) {
        if (k < s) sd[k] += sd[k + s];
        __syncthreads();
    }
    if (k == 0) wcomb[256] = sd[0] + bf[0];
}

// h2 tile = tanh(Acat[n,256] @ WT^T + bl2) via MFMA, fused head dots. h2 not stored.
__global__ void k_h2_mfma_dots(const unsigned short* __restrict__ Acat,
                               const unsigned short* __restrict__ WT,
                               const float* __restrict__ bl2,
                               const float* __restrict__ Wla,
                               const float* __restrict__ Wra,
                               const float* __restrict__ wcomb,
                               float2* __restrict__ pp, float2* __restrict__ self, int n) {
    int wave = threadIdx.x >> 6;
    int lane = threadIdx.x & 63;
    int r = lane & 15;
    int g = lane >> 4;
    int rowbase = blockIdx.x * 64 + wave * 16;
    int arow = rowbase + r;
    if (arow > n - 1) arow = n - 1;

    short8 a[8];
    const short* ap = (const short*)(Acat + (size_t)arow * 256 + g * 8);
#pragma unroll
    for (int kk = 0; kk < 8; kk++)
        a[kk] = *(const short8*)(ap + kk * 32);

    float ppa[4] = {0, 0, 0, 0}, ppc[4] = {0, 0, 0, 0};
    float pra[4] = {0, 0, 0, 0}, prc[4] = {0, 0, 0, 0};

#pragma unroll
    for (int nt = 0; nt < 8; nt++) {
        f32x4 acc = {0.f, 0.f, 0.f, 0.f};
        const short* bp = (const short*)(WT + (size_t)(nt * 16 + r) * 256 + g * 8);
#pragma unroll
        for (int kk = 0; kk < 8; kk++) {
            short8 b = *(const short8*)(bp + kk * 32);
            acc = __builtin_amdgcn_mfma_f32_16x16x32_bf16(a[kk], b, acc, 0, 0, 0);
        }
        int col = nt * 16 + r;
        float bj  = bl2[col];
        float wa  = Wla[col];
        float wra = Wra[col];
        float wcl = wcomb[col];
        float wcr = wcomb[128 + col];
#pragma unroll
        for (int q = 0; q < 4; q++) {
            float t = tanhf(acc[q] + bj);
            ppa[q] += t * wa;
            ppc[q] += t * wcl;
            pra[q] += t * wra;
            prc[q] += t * wcr;
        }
    }
#pragma unroll
    for (int q = 0; q < 4; q++) {
#pragma unroll
        for (int off = 8; off >= 1; off >>= 1) {
            ppa[q] += __shfl_xor(ppa[q], off);
            ppc[q] += __shfl_xor(ppc[q], off);
            pra[q] += __shfl_xor(pra[q], off);
            prc[q] += __shfl_xor(prc[q], off);
        }
    }
    if (r == 0) {
#pragma unroll
        for (int q = 0; q < 4; q++) {
            int rr = rowbase + g * 4 + q;
            if (rr < n) {
                pp[rr]   = make_float2(ppa[q], ppc[q]);
                self[rr] = make_float2(pra[q], prc[q]);
            }
        }
    }
}

__global__ void k_sagg(const float2* __restrict__ pp, const float2* __restrict__ self,
                       const int* __restrict__ row_ptr, const int* __restrict__ edge_src,
                       const float* __restrict__ inv_deg, const float* __restrict__ x,
                       const float* __restrict__ bla, const float* __restrict__ wcomb,
                       float* __restrict__ actor_s, float* __restrict__ critic_v, int n) {
    int i = blockIdx.x * 256 + threadIdx.x;
    if (i >= n) return;
    int s = row_ptr[i], e = row_ptr[i + 1];
    float sa = 0.f, sc = 0.f;
    for (int t = s; t < e; ++t) {
        float2 v = pp[edge_src[t]];
        sa += v.x; sc += v.y;
    }
    float iv = inv_deg[i];
    float2 sf = self[i];
    float a = sa * iv + sf.x + bla[0];
    if (x[(size_t)i * 5 + 2] != 0.0f) a = -INFINITY;
    actor_s[i] = a;
    critic_v[i] = sc * iv + sf.y + wcomb[256];
}

__global__ void k_reduce(const float* __restrict__ actor_s, const float* __restrict__ critic_v,
                         float* __restrict__ scalars, float* __restrict__ d_out, int n) {
    __shared__ float sm[1024], ss[1024], sc[1024];
    int t = threadIdx.x;
    float m = -INFINITY, sum = 0.f, cs = 0.f;
    for (int i = t; i < n; i += 1024) {
        cs += critic_v[i];
        float s = actor_s[i];
        if (s == -INFINITY) continue;
        if (s > m) {
            sum = sum * expf(m - s);
            m = s;
        }
        sum += expf(s - m);
    }
    sm[t] = m; ss[t] = sum; sc[t] = cs;
    __syncthreads();
    for (int s2 = 512; s2 > 0; s2 >>= 1) {
        if (t < s2) {
            float m2 = sm[t + s2], v2 = ss[t + s2];
            float M = fmaxf(sm[t], m2);
            if (M == -INFINITY) {
                ss[t] = 0.f;
            } else {
                ss[t] = ss[t] * expf(sm[t] - M) + v2 * expf(m2 - M);
            }
            sm[t] = M;
            sc[t] += sc[t + s2];
        }
        __syncthreads();
    }
    if (t == 0) {
        scalars[0] = sm[0] + logf(ss[0]);
        d_out[n] = tanhf(sc[0] / (float)n);
    }
}

__global__ void k_final(const float* __restrict__ actor_s, const float* __restrict__ scalars,
                        float* __restrict__ d_out, int n) {
    int i = blockIdx.x * 256 + threadIdx.x;
    if (i >= n) return;
    d_out[i] = actor_s[i] - scalars[0];
}

extern "C" void kernel_launch(void* const* d_in, const int* in_sizes, int n_in,
                              void* d_out, int out_size, void* d_ws, size_t ws_size,
                              hipStream_t stream) {
    const float* x   = (const float*)d_in[0];
    const int*   ei  = (const int*)d_in[1];
    const float* Wl1 = (const float*)d_in[3];
    const float* bl1 = (const float*)d_in[4];
    const float* Wr1 = (const float*)d_in[5];
    const float* Wl2 = (const float*)d_in[6];
    const float* bl2 = (const float*)d_in[7];
    const float* Wr2 = (const float*)d_in[8];
    const float* Wla = (const float*)d_in[9];
    const float* bla = (const float*)d_in[10];
    const float* Wra = (const float*)d_in[11];
    const float* Wlc = (const float*)d_in[12];
    const float* blc = (const float*)d_in[13];
    const float* Wrc = (const float*)d_in[14];
    const float* Wf  = (const float*)d_in[15];
    const float* bf  = (const float*)d_in[16];

    const int n = in_sizes[0] / 5;
    const int E = in_sizes[1] / 2;
    const int NB = (n + NPB - 1) >> NPB_SHIFT;  // 391 for n=50000 (fits MAXNB=512)
    float* out = (float*)d_out;

    char* w = (char*)d_ws;
    auto alloc = [&](size_t bytes) -> void* {
        void* p = (void*)w;
        w += (bytes + 255) & ~(size_t)255;
        return p;
    };
    int* partial     = (int*)alloc((size_t)MAXNB * HBLK * 4);
    int* bucket_base = (int*)alloc((size_t)(MAXNB + 1) * 4);
    int* bucket_cur  = (int*)alloc((size_t)MAXNB * 4);
    unsigned int* binned = (unsigned int*)alloc((size_t)E * 4);
    int* row_ptr  = (int*)alloc((size_t)(n + 1) * 4);
    int* edge_src = (int*)alloc((size_t)E * 4);
    float* inv_deg = (float*)alloc((size_t)n * 4);
    float* agg0    = (float*)alloc((size_t)n * 5 * 4);
    unsigned short* Acat = (unsigned short*)alloc((size_t)n * 256 * 2);  // [agg1 | h1] bf16
    unsigned int* H1f8u  = (unsigned int*)alloc((size_t)n * 128);       // h1 fp8 copy
    unsigned short* WT   = (unsigned short*)alloc((size_t)128 * 256 * 2);
    float2* pp     = (float2*)alloc((size_t)n * 8);
    float2* selfb  = (float2*)alloc((size_t)n * 8);
    float* actor_s = (float*)alloc((size_t)n * 4);
    float* critic_v= (float*)alloc((size_t)n * 4);
    float* wcomb   = (float*)alloc(260 * 4);
    float* scalars = (float*)alloc(16);

    const int nbN = (n + 255) / 256;

    kb_hist<<<HBLK, 256, 0, stream>>>(ei, partial, E, NB);
    kb_scan<<<1, MAXNB, 0, stream>>>(partial, bucket_base, bucket_cur, NB);
    kb_bin<<<(E + CHUNK - 1) / CHUNK, 256, 0, stream>>>(ei, bucket_cur, binned, E, NB);
    kb_csr<<<NB, NPB, 0, stream>>>(binned, bucket_base, row_ptr, inv_deg, edge_src, n, NB);

    k_agg0<<<nbN, 256, 0, stream>>>(x, row_ptr, edge_src, inv_deg, agg0, n);
    k_h1<<<(n + 7) / 8, dim3(32, 8), 0, stream>>>(x, agg0, Wl1, bl1, Wr1, Acat, H1f8u, n);

    k_aggc<<<(n + 15) / 16, 256, 0, stream>>>(H1f8u, row_ptr, edge_src, inv_deg, Acat, n, 0);
    k_aggc<<<(n + 15) / 16, 256, 0, stream>>>(H1f8u, row_ptr, edge_src, inv_deg, Acat, n, 1);

    k_prepw<<<128, 256, 0, stream>>>(Wl2, Wr2, WT);
    k_prep<<<1, 128, 0, stream>>>(Wlc, blc, Wrc, Wf, bf, wcomb);
    k_h2_mfma_dots<<<(n + 63) / 64, 256, 0, stream>>>(Acat, WT, bl2, Wla, Wra, wcomb,
                                                      pp, selfb, n);

    k_sagg<<<nbN, 256, 0, stream>>>(pp, selfb, row_ptr, edge_src, inv_deg, x,
                                    bla, wcomb, actor_s, critic_v, n);
    k_reduce<<<1, 1024, 0, stream>>>(actor_s, critic_v, scalars, out, n);
    k_final<<<nbN, 256, 0, stream>>>(actor_s, scalars, out, n);
}